// Round 11
// baseline (99.497 us; speedup 1.0000x reference)
//
#include <hip/hip_runtime.h>

// SPH pressure-gradient segmented scatter-reduce. i is SORTED.
// R11: atomic-elimination test. CHUNK=1, pure wave segmented scan (no
// per-thread interior flushes -> clean ownership proof):
//   - interior segments (end inside wave, != wave's first particle) are
//     EXCLUSIVE to the wave -> plain float2 store, no RMW.
//   - wave-boundary segments (first-particle partial, lane-63 partial) spill
//     to ws; a tiny fixup kernel atomically folds ~250k entries (vs 1.75M
//     device-scope RMWs before).
// pv gather (the transaction wall, ~73% of line-requests) unchanged.
// Pre-commit: flat result => pv-gather wall confirmed => ROOFLINE.

constexpr float PI_F = 3.14159265358979323846f;

typedef float vfloat2 __attribute__((ext_vector_type(2)));

__global__ __launch_bounds__(256) void prep_kernel(
    const float* __restrict__ p,
    const float* __restrict__ V,
    float2*      __restrict__ pv,
    float2*      __restrict__ out,
    int N)
{
    int n = blockIdx.x * blockDim.x + threadIdx.x;
    if (n < N) {
        pv[n]  = make_float2(p[n], V[n]);
        out[n] = make_float2(0.0f, 0.0f);
    }
}

// OWN=true: ownership stores + spill. OWN=false: fallback atomic path.
template <bool OWN>
__global__ __launch_bounds__(256) void edge_kernel(
    const int*    __restrict__ ei,
    const int*    __restrict__ ej,
    const float*  __restrict__ dirs,   // [E*2] interleaved x,y
    const float*  __restrict__ qarr,
    const float*  __restrict__ support,
    const float*  __restrict__ p_i,
    const float2* __restrict__ pv,     // packed {p, V}
    float2*       __restrict__ out,    // [N], pre-zeroed
    int*          __restrict__ sid,    // [2*nWaves] spill particle ids
    float2*       __restrict__ sval,   // [2*nWaves] spill values
    long long E)
{
    long long e    = blockIdx.x * (long long)blockDim.x + threadIdx.x;
    const int lane = threadIdx.x & 63;
    long long wid  = e >> 6;           // global wave id (blockDim % 64 == 0)

    int   cur = -1;
    float ax = 0.0f, ay = 0.0f;

    if (e < E) {
        const float h    = support[0];
        const float coef = -20.0f * (7.0f / PI_F) / (h * h * h);

        cur = ei[e];                                     // sorted key
        int     jv = __builtin_nontemporal_load(ej + e); // stream
        float   q  = __builtin_nontemporal_load(qarr + e);
        vfloat2 d  = __builtin_nontemporal_load((const vfloat2*)dirs + e);

        float2 pvv = pv[jv];           // random gather (the wall)
        float  piv = p_i[cur];         // near-uniform gather (L1 hits)

        float om = 1.0f - q;
        float w  = (piv + pvv.x) * pvv.y * (coef * q * om * om * om);
        ax = w * d[0];
        ay = w * d[1];
    }

    // wave segmented inclusive scan; keys (cur) sorted, OOB lanes cur=-1.
    #pragma unroll
    for (int d = 1; d < 64; d <<= 1) {
        int   oc  = __shfl_up(cur, d);
        float oax = __shfl_up(ax,  d);
        float oay = __shfl_up(ay,  d);
        if (lane >= d && oc == cur) { ax += oax; ay += oay; }
    }

    int  nxt      = __shfl_down(cur, 1);
    bool seg_end  = (lane == 63) || (nxt != cur);

    if (OWN) {
        int first_cur = __shfl(cur, 0);
        int last_cur  = __shfl(cur, 63);

        // slot1: lane 63's (possibly partial) last segment — always written.
        if (lane == 63) {
            sid [2 * wid + 1] = cur;   // cur may be -1 (OOB wave tail): fixup skips
            sval[2 * wid + 1] = make_float2(ax, ay);
        }
        // slot0: end of the wave's first segment (at lane<63). If the wave is
        // single-segment, no such lane exists -> lane 0 invalidates the slot.
        if (lane == 0 && last_cur == first_cur) {
            sid[2 * wid] = -1;
        }
        if (seg_end && lane < 63 && cur >= 0) {
            if (cur == first_cur) {
                sid [2 * wid] = cur;
                sval[2 * wid] = make_float2(ax, ay);
            } else {
                // interior segment: this wave is the EXCLUSIVE owner of cur
                out[cur] = make_float2(ax, ay);
            }
        }
    } else {
        if (seg_end && cur >= 0) {
            float* acc = (float*)out;
            atomicAdd(&acc[2 * cur],     ax);
            atomicAdd(&acc[2 * cur + 1], ay);
        }
    }
}

__global__ __launch_bounds__(256) void fixup_kernel(
    const int*    __restrict__ sid,
    const float2* __restrict__ sval,
    float*        __restrict__ acc,    // (float*)out
    int nSpill)
{
    int t = blockIdx.x * blockDim.x + threadIdx.x;
    if (t < nSpill) {
        int id = sid[t];
        if (id >= 0) {
            float2 v = sval[t];
            atomicAdd(&acc[2 * id],     v.x);
            atomicAdd(&acc[2 * id + 1], v.y);
        }
    }
}

__global__ __launch_bounds__(256) void finalize_kernel(
    float2* __restrict__ out,
    const float* __restrict__ rhoi,
    int N)
{
    int n = blockIdx.x * blockDim.x + threadIdx.x;
    if (n < N) {
        float2 a  = out[n];
        float  sc = -1.0f / rhoi[n];
        out[n] = make_float2(a.x * sc, a.y * sc);
    }
}

extern "C" void kernel_launch(void* const* d_in, const int* in_sizes, int n_in,
                              void* d_out, int out_size, void* d_ws, size_t ws_size,
                              hipStream_t stream)
{
    // 0:i 1:j 2:ri 3:rj 4:Vi 5:Vj 6:distances 7:radialDistances
    // 8:support 9:numParticles 10:eps 11:rhoi 12:rhoj 13:pi 14:pj
    const int*   ei      = (const int*)  d_in[0];
    const int*   ej      = (const int*)  d_in[1];
    const float* Vj      = (const float*)d_in[5];
    const float* dirs    = (const float*)d_in[6];
    const float* qarr    = (const float*)d_in[7];
    const float* support = (const float*)d_in[8];
    const float* rhoi    = (const float*)d_in[11];
    const float* p_i     = (const float*)d_in[13];
    const float* p_j     = (const float*)d_in[14];

    const long long E = in_sizes[0];
    const int       N = in_sizes[11];

    const long long nWaves = (E + 63) / 64;
    const long long nSpill = 2 * nWaves;

    // ws layout: pv[N] float2 | sid[nSpill] int | sval[nSpill] float2
    size_t pv_bytes  = (size_t)N * sizeof(float2);
    size_t sid_bytes = ((size_t)nSpill * sizeof(int) + 15) & ~(size_t)15;
    size_t need      = pv_bytes + sid_bytes + (size_t)nSpill * sizeof(float2);

    float2* pv   = (float2*)d_ws;
    int*    sid  = (int*)((char*)d_ws + pv_bytes);
    float2* sval = (float2*)((char*)d_ws + pv_bytes + sid_bytes);
    const bool own = (ws_size >= need);

    const int block = 256;

    prep_kernel<<<(N + block - 1) / block, block, 0, stream>>>(
        p_j, Vj, pv, (float2*)d_out, N);

    const int grid = (int)((E + block - 1) / block);
    if (own) {
        edge_kernel<true ><<<grid, block, 0, stream>>>(
            ei, ej, dirs, qarr, support, p_i, pv, (float2*)d_out, sid, sval, E);
        fixup_kernel<<<(int)((nSpill + block - 1) / block), block, 0, stream>>>(
            sid, sval, (float*)d_out, (int)nSpill);
    } else {
        edge_kernel<false><<<grid, block, 0, stream>>>(
            ei, ej, dirs, qarr, support, p_i, pv, (float2*)d_out, sid, sval, E);
    }

    finalize_kernel<<<(N + block - 1) / block, block, 0, stream>>>(
        (float2*)d_out, rhoi, N);
}